// Round 10
// baseline (1661.952 us; speedup 1.0000x reference)
//
#include <hip/hip_runtime.h>

// 4-layer LSTM (B=1024,T=512,H=64,G=256) + FC head.
// 64 blocks x 1024 threads: block = 16-row batch chunk; wave-group (4 waves) = layer.
// Layers pipelined INSIDE the block (skew 1 superstep/layer); handoff via double-buffered
// swizzled LDS tiles + one __syncthreads per superstep. No cross-block sync, no d_ws.
// (r1-r9 measured: cross-block rings cost ~1500cyc/boundary/step regardless of protocol;
//  intra-block barrier-only overhead is ~500-1100cyc. This is the r4 structure, 852us.)
//
// ROUND-10 CHANGE: transcendental-free LSTM cell via exact Pade[5/4] of tanh:
//   tanh(x) ~= x*(945+105u+u^2)/(945+420u+15u^2), u=x^2, input clamped to [-4,4]
//   (max err 1.2e-3 near |x|~3.5-4; ~1e-6 in the typical |pre|<1.5 regime).
//   sigmoid(x) = (1+tanh(x/2))/2 = (N+D)/(2D) with the 1/2 folded into i,f,o weights.
//   Shared denominators: c' = (Nf*c*Di*Dg + Ni*Ng*Df)/(2*Df*Di*Dg),
//   h = No*Nt/(2*Do*Dt) -> 2 v_rcp per cell instead of 10 trans (40->8 trans/lane-step).
//   Measured basis: r4's step = 4 waves x 718 cyc VALU + 1100 stall; trans were 640
//   of the 718. Predicted step ~2900 cyc -> ~640us.

#define TLEN 512
#define NCH  64

typedef __bf16 bf16x8 __attribute__((ext_vector_type(8)));
typedef float  f32x4  __attribute__((ext_vector_type(4)));

struct Params {
  const float* x;
  const float* wih[4]; const float* whh[4];
  const float* bih[4]; const float* bhh[4];
  const float* fc1w; const float* fc1b;
  const float* fc2w; const float* fc2b;
  float* out;
};

__device__ __forceinline__ bf16x8 bfzero() {
  union { unsigned long long u[2]; bf16x8 v; } z; z.u[0] = 0ull; z.u[1] = 0ull; return z.v;
}

// Pade[5/4] tanh(y) = N/D on clamped y (exact continued-fraction integers).
__device__ __forceinline__ void pade_tanh(float x, float& N, float& D) {
  float y = fminf(fmaxf(x, -4.f), 4.f);
  float u = y * y;
  float s = __builtin_fmaf(u, 105.f, 945.f);
  float num = __builtin_fmaf(u, u, s);          // u^2 + 105u + 945
  float d1 = __builtin_fmaf(u, 15.f, 420.f);
  D = __builtin_fmaf(u, d1, 945.f);             // 15u^2 + 420u + 945
  N = y * num;
}

__global__ __launch_bounds__(1024) void lstm_fused(Params p)
{
  const int chunk = blockIdx.x;      // 16-row batch chunk
  const int b0   = chunk * 16;
  const int tid  = threadIdx.x;
  const int wave = tid >> 6;
  const int L    = wave >> 2;        // layer = wave group
  const int w    = wave & 3;         // cols [16w,16w+16) of each gate
  const int lane = tid & 63;
  const int quad = lane >> 4;
  const int l15  = lane & 15;

  // tiles: [parity][0..4]; tile 0 = x (K-padded), tile L+1 = layer L's h. Swizzled 16x64.
  __shared__ __bf16 tiles[2][5][16 * 64];
  __shared__ float  s_fc1w[2048];
  __shared__ float  s_z[512];
  __shared__ float  s_fc1b[32];
  __shared__ float  s_fc2w[96];
  __shared__ float  s_fc2b[3];

  // ---- weight fragments wf[gate][chunk]: 0-1 = Wih(K0..63), 2-3 = Whh(K0..63) ----
  // sigmoid-via-tanh(x/2): fold 0.5 into i,f,o weights+bias; g unscaled.
  bf16x8 wf[4][4];
  float  bias[4];
  {
    const float gsc[4] = { 0.5f, 0.5f, 1.0f, 0.5f };
    const float* wih = p.wih[L];
    const float* whh = p.whh[L];
    const float* bih = p.bih[L];
    const float* bhh = p.bhh[L];
#pragma unroll
    for (int g = 0; g < 4; g++) {
      const float sc = gsc[g];
      int n = g * 64 + w * 16 + l15;   // B-frag: lane&15 = n, k = 32*chunk + quad*8 + j
      bias[g] = (bih[n] + bhh[n]) * sc;
      if (L == 0) {                    // w_ih_0 is (256,4): K-pad to 64 with zeros
        bf16x8 f = bfzero();
        if (quad == 0) {
#pragma unroll
          for (int j = 0; j < 4; j++) f[j] = (__bf16)(wih[n * 4 + j] * sc);
        }
        wf[g][0] = f; wf[g][1] = bfzero();
      } else {
#pragma unroll
        for (int q = 0; q < 2; q++) {
          const float* s = wih + n * 64 + q * 32 + quad * 8;
          bf16x8 f;
#pragma unroll
          for (int j = 0; j < 8; j++) f[j] = (__bf16)(s[j] * sc);
          wf[g][q] = f;
        }
      }
#pragma unroll
      for (int q = 0; q < 2; q++) {
        const float* s = whh + n * 64 + q * 32 + quad * 8;
        bf16x8 f;
#pragma unroll
        for (int j = 0; j < 8; j++) f[j] = (__bf16)(s[j] * sc);
        wf[g][2 + q] = f;
      }
    }
  }

  { // zero all tiles, both parities (x-tile K-padding + zero pipeline-fill reads)
    int* ti = (int*)tiles;
    for (int i = tid; i < 5120; i += 1024) ti[i] = 0;
  }
  float cst[4] = {0.f, 0.f, 0.f, 0.f};

  // x for t=0 -> tiles[0][0]; row r, k=0..3 at r*64 + (r&7)*8 + k (sg = r&7 pattern).
  if (wave == 0 && quad == 0) {
    const float4 xv = *(const float4*)(p.x + ((size_t)(b0 + l15) * TLEN) * 4);
    __bf16 v[4] = {(__bf16)xv.x, (__bf16)xv.y, (__bf16)xv.z, (__bf16)xv.w};
    *(float2*)&tiles[0][0][l15 * 64 + (l15 & 7) * 8] = *(float2*)v;
  }
  __syncthreads();

  for (int s = 0; s < TLEN + 3; s++) {
    const int t  = s - L;
    const int pr = s & 1;
    const int pw = pr ^ 1;

    if ((unsigned)t < (unsigned)TLEN) {
      // A-frags (lane&15 = row, k = 32q + quad*8 + j), swizzled reads
      const __bf16* in  = tiles[pr][L];
      const __bf16* own = tiles[pr][L + 1];
      const int sg0 = quad ^ (l15 & 7);
      const int sg1 = (4 + quad) ^ (l15 & 7);
      bf16x8 xf0 = *(const bf16x8*)&in [l15 * 64 + sg0 * 8];
      bf16x8 xf1 = *(const bf16x8*)&in [l15 * 64 + sg1 * 8];
      bf16x8 hf0 = *(const bf16x8*)&own[l15 * 64 + sg0 * 8];
      bf16x8 hf1 = *(const bf16x8*)&own[l15 * 64 + sg1 * 8];

      f32x4 acc[4];
#pragma unroll
      for (int g = 0; g < 4; g++) { f32x4 a = {bias[g], bias[g], bias[g], bias[g]}; acc[g] = a; }
#pragma unroll
      for (int g = 0; g < 4; g++) {
        acc[g] = __builtin_amdgcn_mfma_f32_16x16x32_bf16(xf0, wf[g][0], acc[g], 0, 0, 0);
        acc[g] = __builtin_amdgcn_mfma_f32_16x16x32_bf16(xf1, wf[g][1], acc[g], 0, 0, 0);
        acc[g] = __builtin_amdgcn_mfma_f32_16x16x32_bf16(hf0, wf[g][2], acc[g], 0, 0, 0);
        acc[g] = __builtin_amdgcn_mfma_f32_16x16x32_bf16(hf1, wf[g][3], acc[g], 0, 0, 0);
      }

      // refresh x tile for t+1 while MFMAs are in flight (layer 0, wave 0 only)
      if (wave == 0 && quad == 0 && t + 1 < TLEN) {
        const float4 xv = *(const float4*)(p.x + ((size_t)(b0 + l15) * TLEN + (t + 1)) * 4);
        __bf16 v[4] = {(__bf16)xv.x, (__bf16)xv.y, (__bf16)xv.z, (__bf16)xv.w};
        *(float2*)&tiles[pw][0][l15 * 64 + (l15 & 7) * 8] = *(float2*)v;
      }

      // per-lane cell (Pade rational, shared denominators, 2 rcp/cell):
      // lane holds (row m = quad*4+r, col = w*16+l15); acc0..3 = i/2, f/2, g, o/2 pre-acts.
      const int col = w * 16 + l15;
      __bf16* dst = tiles[pw][L + 1];
#pragma unroll
      for (int r = 0; r < 4; r++) {
        float Ni, Di, Nf, Df, Ng, Dg, No, Do;
        pade_tanh(acc[0][r], Ni, Di); Ni += Di;   // sigma_i = Ni/(2*Di)
        pade_tanh(acc[1][r], Nf, Df); Nf += Df;   // sigma_f = Nf/(2*Df)
        pade_tanh(acc[2][r], Ng, Dg);             // g = Ng/Dg
        pade_tanh(acc[3][r], No, Do); No += Do;   // sigma_o = No/(2*Do)

        // c' = f*c + i*g = (Nf*c*Di*Dg + Ni*Ng*Df) / (2*Df*Di*Dg)
        float P1   = Di * Dg;
        float T2   = (Nf * cst[r]) * P1;
        float NumC = __builtin_fmaf(Ni * Ng, Df, T2);
        float D1   = Df * P1;
        float c    = 0.5f * (NumC * __builtin_amdgcn_rcpf(D1));
        cst[r] = c;

        float Nt, Dt;
        pade_tanh(c, Nt, Dt);                      // tanh(c) = Nt/Dt
        // h = sigma_o * tanh(c) = No*Nt / (2*Do*Dt)
        float h = 0.5f * ((No * Nt) * __builtin_amdgcn_rcpf(Do * Dt));

        int m  = quad * 4 + r;
        int sg = (col >> 3) ^ (m & 7);
        dst[m * 64 + sg * 8 + (col & 7)] = (__bf16)h;
      }
    }

    __syncthreads();   // publish h tiles (and x tile) to the next superstep
  }

  // ---- FC head + softmax. h(t=511, layer 3) written at s=514 -> parity 1.
  for (int i = tid; i < 2048; i += 1024) s_fc1w[i] = p.fc1w[i];
  if (tid < 32) s_fc1b[tid] = p.fc1b[tid];
  if (tid < 96) s_fc2w[tid] = p.fc2w[tid];
  if (tid < 3)  s_fc2b[tid] = p.fc2b[tid];
  __syncthreads();
  if (tid < 512) {
    int m = tid >> 5, u = tid & 31;
    float sacc = s_fc1b[u];
    const float* wrow = &s_fc1w[u * 64];
    const __bf16* hfin = tiles[1][4];
#pragma unroll
    for (int k = 0; k < 64; k++) {
      int sg = (k >> 3) ^ (m & 7);
      sacc += (float)hfin[m * 64 + sg * 8 + (k & 7)] * wrow[k];
    }
    s_z[m * 32 + u] = fmaxf(sacc, 0.f);
  }
  __syncthreads();
  if (tid < 16) {
    int m = tid;
    float lg[3];
#pragma unroll
    for (int v = 0; v < 3; v++) {
      float sv = s_fc2b[v];
#pragma unroll
      for (int u = 0; u < 32; u++) sv += s_z[m * 32 + u] * s_fc2w[v * 32 + u];
      lg[v] = sv;
    }
    float mx = fmaxf(lg[0], fmaxf(lg[1], lg[2]));
    float e0 = __expf(lg[0] - mx), e1 = __expf(lg[1] - mx), e2 = __expf(lg[2] - mx);
    float inv = 1.f / (e0 + e1 + e2);
    float* o = p.out + (size_t)(b0 + m) * 3;
    o[0] = e0 * inv; o[1] = e1 * inv; o[2] = e2 * inv;
  }
}

extern "C" void kernel_launch(void* const* d_in, const int* in_sizes, int n_in,
                              void* d_out, int out_size, void* d_ws, size_t ws_size,
                              hipStream_t stream)
{
  (void)in_sizes; (void)n_in; (void)out_size; (void)d_ws; (void)ws_size;
  Params p;
  p.x = (const float*)d_in[0];
  for (int l = 0; l < 4; l++) {
    p.wih[l] = (const float*)d_in[1 + 4 * l];
    p.whh[l] = (const float*)d_in[2 + 4 * l];
    p.bih[l] = (const float*)d_in[3 + 4 * l];
    p.bhh[l] = (const float*)d_in[4 + 4 * l];
  }
  p.fc1w = (const float*)d_in[17];
  p.fc1b = (const float*)d_in[18];
  p.fc2w = (const float*)d_in[19];
  p.fc2b = (const float*)d_in[20];
  p.out = (float*)d_out;

  hipLaunchKernelGGL(lstm_fused, dim3(NCH), dim3(1024), 0, stream, p);
}

// Round 11
// 867.671 us; speedup vs baseline: 1.9154x; 1.9154x over previous
//
#include <hip/hip_runtime.h>

// 4-layer LSTM (B=1024,T=512,H=64,G=256) + FC head.
// Kernel A (lstm_split): the ROUND-7 champion (807us) with two changes:
//   (a) ANTI-PACKING LDS PAD: +64KB shared (runtime-guarded keep-alive) -> 83.5KB/block,
//       2 blocks no longer fit a CU (160KB). Tests the hypothesis that r7's 128 blocks were
//       packed 2/CU onto 64 CUs (4 waves/SIMD, ~90% local VALU = issue-bound). If true,
//       spreading to 128 CUs halves per-SIMD VALU issue -> ~420us. If false, no-op.
//   (b) exp2 FOLDING (r8-verified math): i,f,o weights+bias scaled by -log2e, g by +2log2e;
//       sigmoid = rcp(1+exp2(acc)), tanh = 1-2*rcp(1+exp2(acc)); tanh(c) pays one mul.
//       Saves the v_mul(log2e) inside every __expf (~40 cyc/wave/step).
// Structure (unchanged, r7-validated): 128 blocks x 512 threads; block = (role, 16-row chunk);
// role 0 = L0+L1 producer, role 1 = L2+L3 consumer + FC head. Intra-block: wave-group = layer,
// skew 1 superstep, LDS tile handoff. Cross-block h1->L2 ring in d_ws (CAP slots), deep start
// gate (10), depth-3 FIFO rotated one superstep after issue, ALL global ops post-barrier.
// Kernel B (lstm_fused): round-4 single-block fallback (852us) if ws too small.

#define TLEN 512
#define NCH  64
#define AG   __HIP_MEMORY_SCOPE_AGENT
#define SPIN_CAP 2000000
#define LOG2E 1.44269504f
#define TWOLOG2E 2.88539008f

typedef __bf16 bf16x8 __attribute__((ext_vector_type(8)));
typedef float  f32x4  __attribute__((ext_vector_type(4)));

struct Params {
  const float* x;
  const float* wih[4]; const float* whh[4];
  const float* bih[4]; const float* bhh[4];
  const float* fc1w; const float* fc1b;
  const float* fc2w; const float* fc2b;
  float* out; char* ws;
  int CAP; int CM;
};

__device__ __forceinline__ bf16x8 bfzero() {
  union { unsigned long long u[2]; bf16x8 v; } z; z.u[0] = 0ull; z.u[1] = 0ull; return z.v;
}
__device__ __forceinline__ float fast_sigmoid(float x) {
  return __builtin_amdgcn_rcpf(1.f + __expf(-x));
}
__device__ __forceinline__ float fast_tanh(float x) {
  float e = __expf(2.f * x);
  return 1.f - 2.f * __builtin_amdgcn_rcpf(e + 1.f);
}
__device__ __forceinline__ void load_frag_pair(const unsigned short* sb, int l15, int quad,
                                               bf16x8& f0, bf16x8& f1) {
  const unsigned long long* a = (const unsigned long long*)(sb + l15 * 64 + quad * 8);
  const unsigned long long* b = (const unsigned long long*)(sb + l15 * 64 + 32 + quad * 8);
  union { bf16x8 v; unsigned long long u[2]; } c0, c1;
  c0.u[0] = __hip_atomic_load(&a[0], __ATOMIC_RELAXED, AG);
  c0.u[1] = __hip_atomic_load(&a[1], __ATOMIC_RELAXED, AG);
  c1.u[0] = __hip_atomic_load(&b[0], __ATOMIC_RELAXED, AG);
  c1.u[1] = __hip_atomic_load(&b[1], __ATOMIC_RELAXED, AG);
  f0 = c0.v; f1 = c1.v;
}

// ---------------- Kernel A: r7 champion + anti-packing pad + exp2 folding ----------------
__global__ __launch_bounds__(512, 2) void lstm_split(Params p)
{
  const int bid   = blockIdx.x;
  const int role  = bid >> 6;
  const int chunk = bid & 63;
  const int b0    = chunk * 16;
  const int tid   = threadIdx.x;
  const int wave  = tid >> 6;
  const int grp   = wave >> 2;
  const int w     = wave & 3;
  const int lane  = tid & 63;
  const int quad  = lane >> 4;
  const int l15   = lane & 15;
  const int L     = role * 2 + grp;

  __shared__ __bf16 tiles[2][2][1024];
  __shared__ float  s_fc1w[2048];
  __shared__ float  s_z[512];
  __shared__ float  s_fc1b[32];
  __shared__ float  s_fc2w[96];
  __shared__ float  s_fc2b[3];
  __shared__ char   anti_pack_pad[64 * 1024];   // forces <=1 block/CU (83.5KB > 160/2)

  // keep-alive: runtime-false guard so the compiler can't elide the pad
  if (p.CAP == -12345) anti_pack_pad[tid] = (char)tid;

  int* flagp = (int*)p.ws + chunk * 16;
  int* ackp  = (int*)(p.ws + 16 * 1024) + chunk * 16;
  unsigned short* ringc = (unsigned short*)(p.ws + 32 * 1024) + (size_t)chunk * p.CAP * 1024;
  const int CAP = p.CAP, CM = p.CM;

  // ---- weight fragments wf[gate][chunk]: 0-1 = Wih(K0..63), 2-3 = Whh(K0..63) ----
  // exp2 folding: i,f,o scaled -log2e (sigma = rcp(1+exp2(acc)));
  //               g scaled +2log2e (tanh = 1-2*rcp(1+exp2(acc))).
  bf16x8 wf[4][4];
  float  bias[4];
  {
    const float gsc[4] = { -LOG2E, -LOG2E, TWOLOG2E, -LOG2E };
    const float* wih = p.wih[L];
    const float* whh = p.whh[L];
    const float* bih = p.bih[L];
    const float* bhh = p.bhh[L];
#pragma unroll
    for (int g = 0; g < 4; g++) {
      const float sc = gsc[g];
      int n = g * 64 + w * 16 + l15;   // B-frag: lane&15 = n, k = 32*chunk + quad*8 + j
      bias[g] = (bih[n] + bhh[n]) * sc;
      if (L == 0) {                    // w_ih_0 is (256,4): K-pad, chunk1 unused
        bf16x8 f = bfzero();
        if (quad == 0) {
#pragma unroll
          for (int j = 0; j < 4; j++) f[j] = (__bf16)(wih[n * 4 + j] * sc);
        }
        wf[g][0] = f; wf[g][1] = bfzero();
      } else {
#pragma unroll
        for (int q = 0; q < 2; q++) {
          const float* s = wih + n * 64 + q * 32 + quad * 8;
          bf16x8 f;
#pragma unroll
          for (int j = 0; j < 8; j++) f[j] = (__bf16)(s[j] * sc);
          wf[g][q] = f;
        }
      }
#pragma unroll
      for (int q = 0; q < 2; q++) {
        const float* s = whh + n * 64 + q * 32 + quad * 8;
        bf16x8 f;
#pragma unroll
        for (int j = 0; j < 8; j++) f[j] = (__bf16)(s[j] * sc);
        wf[g][2 + q] = f;
      }
    }
  }

  { int* ti = (int*)tiles; for (int i = tid; i < 2048; i += 512) ti[i] = 0; }
  float cst[4] = {0.f, 0.f, 0.f, 0.f};

  int W = -1000000000, f_pend = -1000000000;
  int ackW = -1000000000, a_pend = -1000000000;
  bf16x8 xA0 = bfzero(), xA1 = bfzero();
  bf16x8 xB0 = bfzero(), xB1 = bfzero();
  bf16x8 xC0 = bfzero(), xC1 = bfzero();
  float4 xraw = {0.f, 0.f, 0.f, 0.f};

  if (role == 0) {
    if (grp == 0 && quad == 0) {
      const float* xb = p.x + (size_t)(b0 + l15) * TLEN * 4;
      const float4 x0 = *(const float4*)(xb);
      const float4 x1 = *(const float4*)(xb + 4);
      xraw = *(const float4*)(xb + 8);
      bf16x8 f = bfzero();
      f[0] = (__bf16)x0.x; f[1] = (__bf16)x0.y; f[2] = (__bf16)x0.z; f[3] = (__bf16)x0.w;
      xA0 = f;
      bf16x8 g = bfzero();
      g[0] = (__bf16)x1.x; g[1] = (__bf16)x1.y; g[2] = (__bf16)x1.z; g[3] = (__bf16)x1.w;
      xB0 = g;
    }
  } else if (grp == 0) {
    int v = -1000000000, it = 0;
    do {
      if (lane == 0) v = __hip_atomic_load(flagp, __ATOMIC_ACQUIRE, AG);
      v = __shfl(v, 0);
      if (v >= 10) break;
      __builtin_amdgcn_s_sleep(1);
    } while (++it < SPIN_CAP);
    W = v;
    load_frag_pair(ringc,        l15, quad, xA0, xA1);
    load_frag_pair(ringc + 1024, l15, quad, xB0, xB1);
    load_frag_pair(ringc + 2048, l15, quad, xC0, xC1);
  }
  __syncthreads();

  const int SMAX = (role == 0) ? (TLEN + 2) : (TLEN + 1);
  for (int s = 0; s < SMAX; s++) {
    const int t  = s - grp;
    const int pr = s & 1, pw = pr ^ 1;
    unsigned hb[4];

    if ((unsigned)t < (unsigned)TLEN) {
      bf16x8 if0, if1;
      if (grp == 0) { if0 = xA0; if1 = xA1; }
      else {
        const __bf16* src = tiles[pr][0];
        int sg0 = quad ^ (l15 & 7);
        int sg1 = (4 + quad) ^ (l15 & 7);
        if0 = *(const bf16x8*)&src[l15 * 64 + sg0 * 8];
        if1 = *(const bf16x8*)&src[l15 * 64 + sg1 * 8];
      }
      bf16x8 hf0, hf1;
      {
        const __bf16* src = tiles[pr][grp];
        int sg0 = quad ^ (l15 & 7);
        int sg1 = (4 + quad) ^ (l15 & 7);
        hf0 = *(const bf16x8*)&src[l15 * 64 + sg0 * 8];
        hf1 = *(const bf16x8*)&src[l15 * 64 + sg1 * 8];
      }

      f32x4 acc[4];
#pragma unroll
      for (int g = 0; g < 4; g++) { f32x4 a = {bias[g], bias[g], bias[g], bias[g]}; acc[g] = a; }
      if (L == 0) {
#pragma unroll
        for (int g = 0; g < 4; g++)
          acc[g] = __builtin_amdgcn_mfma_f32_16x16x32_bf16(if0, wf[g][0], acc[g], 0, 0, 0);
      } else {
#pragma unroll
        for (int g = 0; g < 4; g++) {
          acc[g] = __builtin_amdgcn_mfma_f32_16x16x32_bf16(if0, wf[g][0], acc[g], 0, 0, 0);
          acc[g] = __builtin_amdgcn_mfma_f32_16x16x32_bf16(if1, wf[g][1], acc[g], 0, 0, 0);
        }
      }
#pragma unroll
      for (int g = 0; g < 4; g++) {
        acc[g] = __builtin_amdgcn_mfma_f32_16x16x32_bf16(hf0, wf[g][2], acc[g], 0, 0, 0);
        acc[g] = __builtin_amdgcn_mfma_f32_16x16x32_bf16(hf1, wf[g][3], acc[g], 0, 0, 0);
      }

      // cell (exp2-folded): acc_i/f/o = -log2e*pre, acc_g = 2log2e*pre
      const int col = w * 16 + l15;
      __bf16* dst = tiles[pw][grp];
#pragma unroll
      for (int r = 0; r < 4; r++) {
        float ig = __builtin_amdgcn_rcpf(1.f + __builtin_amdgcn_exp2f(acc[0][r]));
        float fg = __builtin_amdgcn_rcpf(1.f + __builtin_amdgcn_exp2f(acc[1][r]));
        float gg = 1.f - 2.f * __builtin_amdgcn_rcpf(1.f + __builtin_amdgcn_exp2f(acc[2][r]));
        float og = __builtin_amdgcn_rcpf(1.f + __builtin_amdgcn_exp2f(acc[3][r]));
        float c  = fg * cst[r] + ig * gg;
        cst[r] = c;
        float th = 1.f - 2.f * __builtin_amdgcn_rcpf(1.f + __builtin_amdgcn_exp2f(TWOLOG2E * c));
        float h  = og * th;
        __bf16 hbf = (__bf16)h;
        union { __bf16 b; unsigned short s; } cv; cv.b = hbf;
        hb[r] = cv.s;
        int m  = quad * 4 + r;
        int sg = (col >> 3) ^ (m & 7);
        dst[m * 64 + sg * 8 + (col & 7)] = hbf;
      }
    }

    __syncthreads();  // drains only step-old global traffic + this step's LDS

    // -------- post-barrier cross-block work (fire & forget; consumed >=1 step later) -----
    if (role == 0) {
      if (grp == 0) {
        xA0 = xB0;
        if (quad == 0) {
          bf16x8 f = bfzero();
          f[0] = (__bf16)xraw.x; f[1] = (__bf16)xraw.y;
          f[2] = (__bf16)xraw.z; f[3] = (__bf16)xraw.w;
          xB0 = f;
          if (t + 3 < TLEN)
            xraw = *(const float4*)(p.x + ((size_t)(b0 + l15) * TLEN + (t + 3)) * 4);
        }
      }
      if (grp == 1 && (unsigned)t < (unsigned)TLEN) {
        int am = __shfl(a_pend, 0);
        if (am > ackW) ackW = am;
        if (lane == 0) a_pend = __hip_atomic_load(ackp, __ATOMIC_RELAXED, AG);
        if (t >= CAP && ackW < t - CAP + 1) {
          int v = ackW, it = 0;
          do {
            if (lane == 0) v = __hip_atomic_load(ackp, __ATOMIC_ACQUIRE, AG);
            v = __shfl(v, 0);
            if (v >= t - CAP + 1) break;
            __builtin_amdgcn_s_sleep(1);
          } while (++it < SPIN_CAP);
          ackW = v;
        }
        const int col = w * 16 + l15;
        unsigned* rdst = (unsigned*)(ringc + (size_t)(t & CM) * 1024);
#pragma unroll
        for (int r = 0; r < 4; r++) {
          unsigned v = hb[r];
          unsigned o = (unsigned)__shfl_xor((int)v, 1);
          if ((lane & 1) == 0) {
            int m = quad * 4 + r;
            __hip_atomic_store(&rdst[(m * 64 + col) >> 1], v | (o << 16), __ATOMIC_RELAXED, AG);
          }
        }
      }
      if (tid == 0 && s >= 2)
        __hip_atomic_store(flagp, s - 1, __ATOMIC_RELAXED, AG);
    } else {
      if (grp == 0) {
        int fm = __shfl(f_pend, 0);
        if (fm > W) W = fm;
        if (lane == 0) f_pend = __hip_atomic_load(flagp, __ATOMIC_RELAXED, AG);
        xA0 = xB0; xA1 = xB1; xB0 = xC0; xB1 = xC1;
        if (t + 3 < TLEN) {
          if (W < t + 4) {
            int v = W, it = 0;
            do {
              if (lane == 0) v = __hip_atomic_load(flagp, __ATOMIC_ACQUIRE, AG);
              v = __shfl(v, 0);
              if (v >= t + 4) break;
              __builtin_amdgcn_s_sleep(1);
            } while (++it < SPIN_CAP);
            W = v;
          }
          load_frag_pair(ringc + (size_t)((t + 3) & CM) * 1024, l15, quad, xC0, xC1);
        }
      }
      if (tid == 0)
        __hip_atomic_store(ackp, s + 2, __ATOMIC_RELAXED, AG);
    }
  }

  // ---- FC head + softmax (consumer; L3 final h at superstep 512 -> parity 1) ----
  if (role == 1) {
    for (int i = tid; i < 2048; i += 512) s_fc1w[i] = p.fc1w[i];
    if (tid < 32) s_fc1b[tid] = p.fc1b[tid];
    if (tid < 96) s_fc2w[tid] = p.fc2w[tid];
    if (tid < 3)  s_fc2b[tid] = p.fc2b[tid];
    __syncthreads();
    {
      int m = tid >> 5, u = tid & 31;
      float sacc = s_fc1b[u];
      const float* wrow = &s_fc1w[u * 64];
      const __bf16* hfin = tiles[1][1];
#pragma unroll
      for (int k = 0; k < 64; k++) {
        int sg = (k >> 3) ^ (m & 7);
        sacc += (float)hfin[m * 64 + sg * 8 + (k & 7)] * wrow[k];
      }
      s_z[m * 32 + u] = fmaxf(sacc, 0.f);
    }
    __syncthreads();
    if (tid < 16) {
      int m = tid;
      float lg[3];
#pragma unroll
      for (int v = 0; v < 3; v++) {
        float sv = s_fc2b[v];
#pragma unroll
        for (int u = 0; u < 32; u++) sv += s_z[m * 32 + u] * s_fc2w[v * 32 + u];
        lg[v] = sv;
      }
      float mx = fmaxf(lg[0], fmaxf(lg[1], lg[2]));
      float e0 = __expf(lg[0] - mx), e1 = __expf(lg[1] - mx), e2 = __expf(lg[2] - mx);
      float inv = 1.f / (e0 + e1 + e2);
      float* o = p.out + (size_t)(b0 + m) * 3;
      o[0] = e0 * inv; o[1] = e1 * inv; o[2] = e2 * inv;
    }
  }
}

// =============== Kernel B: round-4 fallback (no ws use) ===============
__global__ __launch_bounds__(1024) void lstm_fused(Params p)
{
  const int chunk = blockIdx.x;
  const int b0   = chunk * 16;
  const int tid  = threadIdx.x;
  const int wave = tid >> 6;
  const int L    = wave >> 2;
  const int w    = wave & 3;
  const int lane = tid & 63;
  const int quad = lane >> 4;
  const int l15  = lane & 15;

  __shared__ __bf16 tiles[2][5][16 * 64];
  __shared__ float  s_fc1w[2048];
  __shared__ float  s_z[512];
  __shared__ float  s_fc1b[32];
  __shared__ float  s_fc2w[96];
  __shared__ float  s_fc2b[3];

  bf16x8 wf[4][4];
  float  bias[4];
  {
    const float* wih = p.wih[L];
    const float* whh = p.whh[L];
    const float* bih = p.bih[L];
    const float* bhh = p.bhh[L];
#pragma unroll
    for (int g = 0; g < 4; g++) {
      int n = g * 64 + w * 16 + l15;
      bias[g] = bih[n] + bhh[n];
      if (L == 0) {
        bf16x8 f = bfzero();
        if (quad == 0) {
#pragma unroll
          for (int j = 0; j < 4; j++) f[j] = (__bf16)wih[n * 4 + j];
        }
        wf[g][0] = f; wf[g][1] = bfzero();
      } else {
#pragma unroll
        for (int q = 0; q < 2; q++) {
          const float* s = wih + n * 64 + q * 32 + quad * 8;
          bf16x8 f;
#pragma unroll
          for (int j = 0; j < 8; j++) f[j] = (__bf16)s[j];
          wf[g][q] = f;
        }
      }
#pragma unroll
      for (int q = 0; q < 2; q++) {
        const float* s = whh + n * 64 + q * 32 + quad * 8;
        bf16x8 f;
#pragma unroll
        for (int j = 0; j < 8; j++) f[j] = (__bf16)s[j];
        wf[g][2 + q] = f;
      }
    }
  }

  { int* ti = (int*)tiles; for (int i = tid; i < 5120; i += 1024) ti[i] = 0; }
  float cst[4] = {0.f, 0.f, 0.f, 0.f};

  if (wave == 0 && quad == 0) {
    const float4 xv = *(const float4*)(p.x + ((size_t)(b0 + l15) * TLEN) * 4);
    __bf16 v[4] = {(__bf16)xv.x, (__bf16)xv.y, (__bf16)xv.z, (__bf16)xv.w};
    *(float2*)&tiles[0][0][l15 * 64 + (l15 & 7) * 8] = *(float2*)v;
  }
  __syncthreads();

  for (int s = 0; s < TLEN + 3; s++) {
    const int t  = s - L;
    const int pr = s & 1;
    const int pw = pr ^ 1;

    if ((unsigned)t < (unsigned)TLEN) {
      const __bf16* in  = tiles[pr][L];
      const __bf16* own = tiles[pr][L + 1];
      const int sg0 = quad ^ (l15 & 7);
      const int sg1 = (4 + quad) ^ (l15 & 7);
      bf16x8 xf0 = *(const bf16x8*)&in [l15 * 64 + sg0 * 8];
      bf16x8 xf1 = *(const bf16x8*)&in [l15 * 64 + sg1 * 8];
      bf16x8 hf0 = *(const bf16x8*)&own[l15 * 64 + sg0 * 8];
      bf16x8 hf1 = *(const bf16x8*)&own[l15 * 64 + sg1 * 8];

      f32x4 acc[4];
#pragma unroll
      for (int g = 0; g < 4; g++) { f32x4 a = {bias[g], bias[g], bias[g], bias[g]}; acc[g] = a; }
#pragma unroll
      for (int g = 0; g < 4; g++) {
        acc[g] = __builtin_amdgcn_mfma_f32_16x16x32_bf16(xf0, wf[g][0], acc[g], 0, 0, 0);
        acc[g] = __builtin_amdgcn_mfma_f32_16x16x32_bf16(xf1, wf[g][1], acc[g], 0, 0, 0);
        acc[g] = __builtin_amdgcn_mfma_f32_16x16x32_bf16(hf0, wf[g][2], acc[g], 0, 0, 0);
        acc[g] = __builtin_amdgcn_mfma_f32_16x16x32_bf16(hf1, wf[g][3], acc[g], 0, 0, 0);
      }

      if (wave == 0 && quad == 0 && t + 1 < TLEN) {
        const float4 xv = *(const float4*)(p.x + ((size_t)(b0 + l15) * TLEN + (t + 1)) * 4);
        __bf16 v[4] = {(__bf16)xv.x, (__bf16)xv.y, (__bf16)xv.z, (__bf16)xv.w};
        *(float2*)&tiles[pw][0][l15 * 64 + (l15 & 7) * 8] = *(float2*)v;
      }

      const int col = w * 16 + l15;
      __bf16* dst = tiles[pw][L + 1];
#pragma unroll
      for (int r = 0; r < 4; r++) {
        float ig = fast_sigmoid(acc[0][r]);
        float fg = fast_sigmoid(acc[1][r]);
        float gg = fast_tanh(acc[2][r]);
        float og = fast_sigmoid(acc[3][r]);
        float c = fg * cst[r] + ig * gg;
        cst[r] = c;
        float h = og * fast_tanh(c);
        int m  = quad * 4 + r;
        int sg = (col >> 3) ^ (m & 7);
        dst[m * 64 + sg * 8 + (col & 7)] = (__bf16)h;
      }
    }
    __syncthreads();
  }

  for (int i = tid; i < 2048; i += 1024) s_fc1w[i] = p.fc1w[i];
  if (tid < 32) s_fc1b[tid] = p.fc1b[tid];
  if (tid < 96) s_fc2w[tid] = p.fc2w[tid];
  if (tid < 3)  s_fc2b[tid] = p.fc2b[tid];
  __syncthreads();
  if (tid < 512) {
    int m = tid >> 5, u = tid & 31;
    float sacc = s_fc1b[u];
    const float* wrow = &s_fc1w[u * 64];
    const __bf16* hfin = tiles[1][4];
#pragma unroll
    for (int k = 0; k < 64; k++) {
      int sg = (k >> 3) ^ (m & 7);
      sacc += (float)hfin[m * 64 + sg * 8 + (k & 7)] * wrow[k];
    }
    s_z[m * 32 + u] = fmaxf(sacc, 0.f);
  }
  __syncthreads();
  if (tid < 16) {
    int m = tid;
    float lg[3];
#pragma unroll
    for (int v = 0; v < 3; v++) {
      float sv = s_fc2b[v];
#pragma unroll
      for (int u = 0; u < 32; u++) sv += s_z[m * 32 + u] * s_fc2w[v * 32 + u];
      lg[v] = sv;
    }
    float mx = fmaxf(lg[0], fmaxf(lg[1], lg[2]));
    float e0 = __expf(lg[0] - mx), e1 = __expf(lg[1] - mx), e2 = __expf(lg[2] - mx);
    float inv = 1.f / (e0 + e1 + e2);
    float* o = p.out + (size_t)(b0 + m) * 3;
    o[0] = e0 * inv; o[1] = e1 * inv; o[2] = e2 * inv;
  }
}

extern "C" void kernel_launch(void* const* d_in, const int* in_sizes, int n_in,
                              void* d_out, int out_size, void* d_ws, size_t ws_size,
                              hipStream_t stream)
{
  (void)in_sizes; (void)n_in; (void)out_size;
  Params p;
  p.x = (const float*)d_in[0];
  for (int l = 0; l < 4; l++) {
    p.wih[l] = (const float*)d_in[1 + 4 * l];
    p.whh[l] = (const float*)d_in[2 + 4 * l];
    p.bih[l] = (const float*)d_in[3 + 4 * l];
    p.bhh[l] = (const float*)d_in[4 + 4 * l];
  }
  p.fc1w = (const float*)d_in[17];
  p.fc1b = (const float*)d_in[18];
  p.fc2w = (const float*)d_in[19];
  p.fc2b = (const float*)d_in[20];
  p.out = (float*)d_out;
  p.ws  = (char*)d_ws;

  // ring: 64 chunks x CAP slots x 2KB = CAP * 128KB, after 32KB flags
  const size_t avail = (ws_size > 32768) ? (ws_size - 32768) : 0;
  int CAP = 1;
  while (CAP < 64 && (size_t)(CAP * 2) * (NCH * 2048ull) <= avail) CAP <<= 1;

  if (CAP >= 16) {
    p.CAP = CAP; p.CM = CAP - 1;
    hipLaunchKernelGGL(lstm_split, dim3(128), dim3(512), 0, stream, p);
  } else {
    p.CAP = 0; p.CM = 0;
    hipLaunchKernelGGL(lstm_fused, dim3(NCH), dim3(1024), 0, stream, p);
  }
}